// Round 1
// baseline (291.434 us; speedup 1.0000x reference)
//
#include <hip/hip_runtime.h>
#include <hip/hip_bf16.h>

// Holonomy: for each (b, n) chain, hol = M_15 @ ... @ M_0, M_t = Gamma[b, loops[n][t+1], loops[n][t]]
// Gamma: [4, 512, 512, 8, 8] fp32 (each 8x8 matrix is a contiguous 64-float block)
// loops: [64, 17] int
// out:   [4, 64, 8, 8] fp32
//
// Mapping: one wave (64 lanes) per chain; lane = r*8+c holds element (r,c) of the
// running holonomy. All 16 gathered matrices are prefetched into registers with
// perfectly coalesced 256B loads (lane i loads element i of the contiguous block),
// then the 16-step chain runs on shuffles only (no LDS).

#define BATCH    4
#define NLOOPS   64
#define SEQ      512
#define LOOPLEN  17
#define NSTEPS   (LOOPLEN - 1)   // 16

__global__ __launch_bounds__(256) void holonomy_kernel(
    const float* __restrict__ Gamma,
    const int*   __restrict__ loops,
    float*       __restrict__ out)
{
    const int lane  = threadIdx.x & 63;
    const int wave  = threadIdx.x >> 6;
    const int chain = blockIdx.x * (blockDim.x >> 6) + wave;   // 0..255
    const int b = chain >> 6;        // chain / NLOOPS
    const int n = chain & 63;        // chain % NLOOPS
    const int r = lane >> 3;
    const int c = lane & 7;

    const int* lp = loops + n * LOOPLEN;

    // Prefetch all 16 matrices: independent loads, one wait.
    // Gamma[b, i, j, :, :] is contiguous: base = ((b*SEQ + i)*SEQ + j)*64
    float m[NSTEPS];
    const int base_b = b * SEQ * SEQ * 64;
#pragma unroll
    for (int t = 0; t < NSTEPS; ++t) {
        const int j = lp[t];
        const int i = lp[t + 1];
        m[t] = Gamma[base_b + (i * SEQ + j) * 64 + lane];
    }

    // hol = I
    float hol = (r == c) ? 1.0f : 0.0f;

    // hol = M_t @ hol ; new[r][c] = sum_k M_t[r][k] * hol[k][c]
#pragma unroll
    for (int t = 0; t < NSTEPS; ++t) {
        float acc = 0.0f;
#pragma unroll
        for (int k = 0; k < 8; ++k) {
            const float a = __shfl(m[t], (lane & 56) + k, 64);  // M_t[r][k]
            const float h = __shfl(hol,  k * 8 + c,      64);   // hol[k][c]
            acc = fmaf(a, h, acc);
        }
        hol = acc;
    }

    out[chain * 64 + lane] = hol;
}

extern "C" void kernel_launch(void* const* d_in, const int* in_sizes, int n_in,
                              void* d_out, int out_size, void* d_ws, size_t ws_size,
                              hipStream_t stream) {
    const float* Gamma = (const float*)d_in[0];
    const int*   loops = (const int*)d_in[1];
    float*       out   = (float*)d_out;

    // 256 chains, one wave each; 4 waves per block -> 64 blocks x 256 threads
    dim3 grid(64), block(256);
    holonomy_kernel<<<grid, block, 0, stream>>>(Gamma, loops, out);
}

// Round 2
// 289.392 us; speedup vs baseline: 1.0071x; 1.0071x over previous
//
#include <hip/hip_runtime.h>
#include <hip/hip_bf16.h>

// Holonomy: for each (b, n) chain, hol = M_15 @ ... @ M_0, M_t = Gamma[b, loops[n][t+1], loops[n][t]]
// Gamma: [4, 512, 512, 8, 8] fp32 (each 8x8 matrix is a contiguous 64-float block)
// loops: [64, 17] int
// out:   [4, 64, 8, 8] fp32
//
// Mapping: one wave per chain, one wave per block (256 blocks x 64 threads) so the
// loop indices are compiler-provably wave-uniform (scalar loads). Lane = r*8+c holds
// element (r,c) of the running holonomy. All 16 gathered matrices prefetched with
// coalesced 256B loads; the 16-step chain runs on ds_bpermute shuffles only.

#define BATCH    4
#define NLOOPS   64
#define SEQ      512
#define LOOPLEN  17
#define NSTEPS   (LOOPLEN - 1)   // 16

__global__ __launch_bounds__(64) void holonomy_kernel(
    const float* __restrict__ Gamma,
    const int*   __restrict__ loops,
    float*       __restrict__ out)
{
    const int lane  = threadIdx.x;        // 0..63
    const int chain = blockIdx.x;         // 0..255
    const int b = chain >> 6;             // chain / NLOOPS
    const int n = chain & 63;             // chain % NLOOPS  (block-uniform -> scalar)
    const int r = lane >> 3;
    const int c = lane & 7;

    const int* lp = loops + n * LOOPLEN;

    // Prefetch all 16 matrices: independent loads, one wait.
    // Gamma[b, i, j, :, :] contiguous: offset = ((b*SEQ + i)*SEQ + j)*64
    float m[NSTEPS];
    const int base_b = b * SEQ * SEQ * 64;
#pragma unroll
    for (int t = 0; t < NSTEPS; ++t) {
        const int j = lp[t];
        const int i = lp[t + 1];
        m[t] = Gamma[base_b + (i * SEQ + j) * 64 + lane];
    }

    // hol = I
    float hol = (r == c) ? 1.0f : 0.0f;

    // hol = M_t @ hol ; new[r][c] = sum_k M_t[r][k] * hol[k][c]
    // Two accumulator chains halve the dependent-FMA latency per step.
#pragma unroll
    for (int t = 0; t < NSTEPS; ++t) {
        float acc0 = 0.0f, acc1 = 0.0f;
#pragma unroll
        for (int k = 0; k < 8; k += 2) {
            const float a0 = __shfl(m[t], (lane & 56) + k,     64);  // M_t[r][k]
            const float h0 = __shfl(hol,  k * 8 + c,           64);  // hol[k][c]
            const float a1 = __shfl(m[t], (lane & 56) + k + 1, 64);
            const float h1 = __shfl(hol,  (k + 1) * 8 + c,     64);
            acc0 = fmaf(a0, h0, acc0);
            acc1 = fmaf(a1, h1, acc1);
        }
        hol = acc0 + acc1;
    }

    out[chain * 64 + lane] = hol;
}

extern "C" void kernel_launch(void* const* d_in, const int* in_sizes, int n_in,
                              void* d_out, int out_size, void* d_ws, size_t ws_size,
                              hipStream_t stream) {
    const float* Gamma = (const float*)d_in[0];
    const int*   loops = (const int*)d_in[1];
    float*       out   = (float*)d_out;

    // 256 chains, one wave each, one wave per block -> spread across all 256 CUs
    dim3 grid(BATCH * NLOOPS), block(64);
    holonomy_kernel<<<grid, block, 0, stream>>>(Gamma, loops, out);
}